// Round 6
// baseline (1930.105 us; speedup 1.0000x reference)
//
#include <hip/hip_runtime.h>
#include <hip/hip_bf16.h>
#include <math.h>

typedef __attribute__((ext_vector_type(8))) short bf16x8;
typedef __attribute__((ext_vector_type(4))) float f32x4;

#define NBATCH   2048
#define MTILES   64          // 32 batches (352 rows) each; 64*352 = 22528 exact
#define NTILES   16          // 192 cols each (12 groups of 16)
#define NBLOCKS  (MTILES*NTILES)
#define LDS_TOTAL 139392     // epilogue stage: 6 regions * 176*33*4 B
#define ABUF0 0              // 22528 B  (352 rows x 32 k x bf16)
#define ABUF1 22528
#define BBUF0 45056          // 12288 B  (192 cols x 32 k x bf16)
#define BBUF1 57344
#define EPI_STRIDE 5808      // floats per region (176*33)

// A pre-packed bf16, MFMA-fragment-linear:
// [mtile 64][kstep 32][granule mf 0..21][lane 64][8]
// lane = hi4*16+lo16 -> row = mtile*352 + mf*16 + lo16 ; k = kstep*32 + hi4*8 + j
__device__ unsigned short g_A[(size_t)MTILES*32*22*64*8];
// B packed bf16 fragment-linear: [g 192][kk 32][lane 64][8]
// col = g*16 + (lane&15) ; k = kk*32 + (lane>>4)*8 + j
// g 0..31 = kW1, 32..63 = lW1, 64..127 = dW1a, 128..191 = dW1b
__device__ unsigned short g_wsB2[(size_t)192*32*64*8];
// partial sums, slot-major: rows 0..15 kinetic pairs; 16 + j*11 + t local (j<16);
// 192 + j2*55 + p interaction (j2<64). col = batch.
__device__ float g_part[(size_t)3712*NBATCH];

static constexpr int II_[55] = {
    0,0,0,0,0,0,0,0,0,0, 1,1,1,1,1,1,1,1,1, 2,2,2,2,2,2,2,2,
    3,3,3,3,3,3,3, 4,4,4,4,4,4, 5,5,5,5,5, 6,6,6,6, 7,7,7, 8,8, 9};
static constexpr int JJ_[55] = {
    1,2,3,4,5,6,7,8,9,10, 2,3,4,5,6,7,8,9,10, 3,4,5,6,7,8,9,10,
    4,5,6,7,8,9,10, 5,6,7,8,9,10, 6,7,8,9,10, 7,8,9,10, 8,9,10, 9,10, 10};

__device__ __forceinline__ unsigned short f32_to_bf16u(float f) {
    unsigned u = __float_as_uint(f);
    u += 0x7fffu + ((u >> 16) & 1u);
    return (unsigned short)(u >> 16);
}

// 96 wave-pairs: pairIdx = ntile*6 + wn. <16 kinetic, <32 local, else interaction.
__device__ __forceinline__ int gmap(int pairIdx, int nf) {
    if (pairIdx < 16) return 2*pairIdx + nf;
    if (pairIdx < 32) return 32 + 2*(pairIdx-16) + nf;
    const int j2 = pairIdx - 32;
    return (nf ? 128 : 64) + j2;
}

__global__ void pack_A(const float* __restrict__ h) {
    const int t = blockIdx.x*256 + threadIdx.x;        // 22528*128 threads
    const int row = t >> 7, k8 = t & 127;
    const float* src = h + (size_t)row*1024 + k8*8;
    f32x4 a = *(const f32x4*)src;
    f32x4 b = *(const f32x4*)(src + 4);
    bf16x8 v;
    v[0]=(short)f32_to_bf16u(a[0]); v[1]=(short)f32_to_bf16u(a[1]);
    v[2]=(short)f32_to_bf16u(a[2]); v[3]=(short)f32_to_bf16u(a[3]);
    v[4]=(short)f32_to_bf16u(b[0]); v[5]=(short)f32_to_bf16u(b[1]);
    v[6]=(short)f32_to_bf16u(b[2]); v[7]=(short)f32_to_bf16u(b[3]);
    const int mtile = row / 352;
    const int rr = row - mtile*352;
    const int mf = rr >> 4, lo = rr & 15;
    const int kstep = k8 >> 2, h4 = k8 & 3;
    const size_t di = ((((size_t)mtile*32 + kstep)*22 + mf)*64 + (h4*16 + lo))*8;
    *(bf16x8*)(g_A + di) = v;
}

__global__ void pack_weights(const float* __restrict__ kW1,
                             const float* __restrict__ lW1,
                             const float* __restrict__ dW1) {
    const int t = blockIdx.x * 256 + threadIdx.x;      // 0..393215
    const int lane = t & 63;
    const int kk   = (t >> 6) & 31;
    const int g    = t >> 11;                           // 0..191
    const int col  = g * 16 + (lane & 15);
    const int k0   = kk * 32 + (lane >> 4) * 8;
    const float* src; int ncol, c;
    if (col < 512)       { src = kW1;                        ncol = 512;  c = col; }
    else if (col < 1024) { src = lW1;                        ncol = 512;  c = col - 512; }
    else if (col < 2048) { src = dW1;                        ncol = 1024; c = col - 1024; }
    else                 { src = dW1 + (size_t)1024 * 1024;  ncol = 1024; c = col - 2048; }
    bf16x8 v;
    #pragma unroll
    for (int j = 0; j < 8; ++j)
        v[j] = (short)f32_to_bf16u(src[(size_t)(k0 + j) * ncol + c]);
    *(bf16x8*)(g_wsB2 + (size_t)t * 8) = v;
}

__launch_bounds__(768, 3)
__global__ void energy_mfma(
    const float* __restrict__ kb1, const float* __restrict__ kW2,
    const float* __restrict__ lb1, const float* __restrict__ lW2,
    const float* __restrict__ db1, const float* __restrict__ dW2)
{
    extern __shared__ char smem[];
    const int tid  = threadIdx.x;
    const int wv   = tid >> 6, ln = tid & 63;
    const int lo16 = ln & 15, hi4 = ln >> 4;
    const int wm   = wv / 6, wn = wv % 6;          // 2M x 6N waves
    const int bx   = blockIdx.x;
    const int x    = bx & 7, bi = bx >> 3;
    const int n    = 2*x + (bi >> 6);              // XCD x handles ntiles {2x, 2x+1}
    const int m    = bi & 63;
    const int pairIdx = n*6 + wn;

    f32x4 acc[11][2];
    #pragma unroll
    for (int mf = 0; mf < 11; ++mf) {
        acc[mf][0] = (f32x4){0.f,0.f,0.f,0.f};
        acc[mf][1] = (f32x4){0.f,0.f,0.f,0.f};
    }

    auto stageOne = [&](int gi, int step, int aOff, int bOff) {
        const char* src; char* dst;
        if (gi < 22) {
            src = (const char*)g_A + ((((size_t)m*32 + step)*22 + gi)*64 + ln)*16;
            dst = smem + aOff + gi*1024;
        } else {
            const int j = gi - 22;
            const int G = gmap(n*6 + (j >> 1), j & 1);
            src = (const char*)g_wsB2 + (((size_t)G*32 + step)*64 + ln)*16;
            dst = smem + bOff + j*1024;
        }
        __builtin_amdgcn_global_load_lds(
            (const __attribute__((address_space(1))) unsigned int*)src,
            (__attribute__((address_space(3))) unsigned int*)dst, 16, 0, 0);
    };
    auto stage = [&](int step, int aOff, int bOff) {
        stageOne(wv,      step, aOff, bOff);
        stageOne(wv + 12, step, aOff, bOff);
        if (wv < 10) stageOne(wv + 24, step, aOff, bOff);   // 34 granules total
    };

    stage(0, ABUF0, BBUF0);
    asm volatile("s_waitcnt vmcnt(0)" ::: "memory");
    __syncthreads();

    int cur = 0;
    #pragma unroll 1
    for (int step = 0; step < 32; ++step) {
        if (step < 31) stage(step + 1, cur ? ABUF0 : ABUF1, cur ? BBUF0 : BBUF1);
        const char* Ab = smem + (cur ? ABUF1 : ABUF0) + (wm*11)*1024 + ln*16;
        const char* Bb = smem + (cur ? BBUF1 : BBUF0) + (wn*2)*1024 + ln*16;
        bf16x8 b0 = *(const bf16x8*)(Bb);
        bf16x8 b1 = *(const bf16x8*)(Bb + 1024);
        __builtin_amdgcn_s_setprio(1);
        #pragma unroll
        for (int mf = 0; mf < 11; ++mf) {
            bf16x8 af = *(const bf16x8*)(Ab + mf*1024);
            acc[mf][0] = __builtin_amdgcn_mfma_f32_16x16x32_bf16(af, b0, acc[mf][0], 0,0,0);
            acc[mf][1] = __builtin_amdgcn_mfma_f32_16x16x32_bf16(af, b1, acc[mf][1], 0,0,0);
        }
        __builtin_amdgcn_s_setprio(0);
        asm volatile("s_waitcnt vmcnt(0)" ::: "memory");
        __syncthreads();
        cur ^= 1;
    }

    // ---------------- epilogue (2 rounds x 6 waves; region per wn) ----------------
    const int bg0 = m*32 + wm*16;
    auto epi = [&]() {
        float* stg = (float*)smem + wn * EPI_STRIDE;   // [176 rows][33]
        if (pairIdx < 32) {
            const bool kin = pairIdx < 16;
            const float* b1a = kin ? kb1 : lb1;
            const float* w2a = kin ? kW2 : lW2;
            const int c0 = (kin ? pairIdx : (pairIdx - 16)) * 32;
            const float b1v0 = b1a[c0 + lo16],      w2v0 = w2a[c0 + lo16];
            const float b1v1 = b1a[c0 + 16 + lo16], w2v1 = w2a[c0 + 16 + lo16];
            #pragma unroll
            for (int mf = 0; mf < 11; ++mf)
                #pragma unroll
                for (int e = 0; e < 4; ++e) {
                    const int r = mf*16 + 4*hi4 + e;
                    stg[r*33 + lo16]      = fmaxf(acc[mf][0][e] + b1v0, 0.f) * w2v0;
                    stg[r*33 + 16 + lo16] = fmaxf(acc[mf][1][e] + b1v1, 0.f) * w2v1;
                }
            asm volatile("s_waitcnt lgkmcnt(0)" ::: "memory");
            float rs0 = 0.f, rs1 = 0.f, rs2 = 0.f;
            #pragma unroll
            for (int c = 0; c < 32; ++c) {
                rs0 += stg[ln*33 + c];
                rs1 += stg[(ln + 64)*33 + c];
                if (ln < 48) rs2 += stg[(ln + 128)*33 + c];
            }
            if (kin) {
                asm volatile("s_waitcnt lgkmcnt(0)" ::: "memory");
                stg[ln] = rs0; stg[ln + 64] = rs1;
                if (ln < 48) stg[ln + 128] = rs2;
                asm volatile("s_waitcnt lgkmcnt(0)" ::: "memory");
                if (ln < 16) {
                    float s = 0.f;
                    #pragma unroll
                    for (int t = 0; t < 11; ++t) s += stg[ln*11 + t];
                    g_part[(size_t)pairIdx*NBATCH + bg0 + ln] = s;
                }
            } else {
                const int base = 16 + (pairIdx - 16)*11;
                { const int r = ln;       const int b = (r*373)>>12; const int t = r - b*11;
                  g_part[(size_t)(base + t)*NBATCH + bg0 + b] = rs0; }
                { const int r = ln + 64;  const int b = (r*373)>>12; const int t = r - b*11;
                  g_part[(size_t)(base + t)*NBATCH + bg0 + b] = rs1; }
                if (ln < 48) {
                  const int r = ln + 128; const int b = (r*373)>>12; const int t = r - b*11;
                  g_part[(size_t)(base + t)*NBATCH + bg0 + b] = rs2; }
            }
        } else {
            const int j2 = pairIdx - 32;
            const float db1v = db1[j2*16 + lo16];
            const float dw2v = dW2[j2*16 + lo16];
            #pragma unroll
            for (int mf = 0; mf < 11; ++mf)
                #pragma unroll
                for (int e = 0; e < 4; ++e) {
                    const int r = mf*16 + 4*hi4 + e;
                    stg[r*33 + lo16]      = acc[mf][0][e];   // pre_i
                    stg[r*33 + 16 + lo16] = acc[mf][1][e];   // pre_j
                }
            asm volatile("s_waitcnt lgkmcnt(0)" ::: "memory");
            #pragma unroll 1
            for (int it = 0; it < 4; ++it) {
                const int b = hi4 + 4*it;                    // batch (local 0..15)
                float pi[11], pj[11];
                #pragma unroll
                for (int t = 0; t < 11; ++t) {
                    pi[t] = stg[(b*11 + t)*33 + lo16] + db1v;
                    pj[t] = stg[(b*11 + t)*33 + 16 + lo16];
                }
                float aP[55];
                #pragma unroll
                for (int p = 0; p < 55; ++p)
                    aP[p] = fmaxf(pi[II_[p]] + pj[JJ_[p]], 0.f) * dw2v;
                #pragma unroll
                for (int p = 0; p < 55; ++p) {               // reduce over d (lo16)
                    aP[p] += __shfl_xor(aP[p], 1);
                    aP[p] += __shfl_xor(aP[p], 2);
                    aP[p] += __shfl_xor(aP[p], 4);
                    aP[p] += __shfl_xor(aP[p], 8);
                }
                const int bg = bg0 + b;
                #pragma unroll
                for (int p = 0; p < 55; ++p)
                    if (lo16 == (p & 15))
                        g_part[(size_t)(192 + j2*55 + p)*NBATCH + bg] = aP[p];
            }
        }
    };
    if (wm == 0) epi();
    __syncthreads();
    if (wm == 1) epi();
}

__global__ void finalize(
    const float* __restrict__ base_conf,
    const float* __restrict__ kb2, const float* __restrict__ lb2,
    const float* __restrict__ db2,
    const float* __restrict__ kwp, const float* __restrict__ lwp,
    const float* __restrict__ iwp, const float* __restrict__ tmpp,
    float* __restrict__ out)
{
    const int b = blockIdx.x*256 + threadIdx.x;
    if (b >= NBATCH) return;
    const float kw = kwp[0], lw = lwp[0], iw = iwp[0], temp = tmpp[0];

    float ks = 0.f;
    #pragma unroll
    for (int s = 0; s < 16; ++s) ks += g_part[(size_t)s*NBATCH + b];
    const float kinetic = -kw * (ks * (1.f/11.f) + kb2[0]);

    float ls = 0.f;
    #pragma unroll 1
    for (int t = 0; t < 11; ++t) {
        float v = lb2[0];
        #pragma unroll
        for (int j = 0; j < 16; ++j) v += g_part[(size_t)(16 + j*11 + t)*NBATCH + b];
        ls += fmaxf(v, 0.f);
    }
    const float local_e = lw * (ls * (1.f/11.f));

    float is = 0.f;
    #pragma unroll 1
    for (int p = 0; p < 55; ++p) {
        float v = db2[0];
        #pragma unroll
        for (int j = 0; j < 64; ++j) v += g_part[(size_t)(192 + j*55 + p)*NBATCH + b];
        is += fmaxf(v, 0.f) * (1.f / (float)(JJ_[p] - II_[p] + 1));
    }
    const float inter = iw * (is * (1.f/55.f));

    const float total = kinetic + local_e + inter;
    const float ec = 1.f / (1.f + expf(total / (fabsf(temp) + 0.1f)));
    out[0*NBATCH + b] = total;
    out[1*NBATCH + b] = kinetic;
    out[2*NBATCH + b] = local_e;
    out[3*NBATCH + b] = inter;
    out[4*NBATCH + b] = ec;
    out[5*NBATCH + b] = base_conf[b] * ec;
}

extern "C" void kernel_launch(void* const* d_in, const int* in_sizes, int n_in,
                              void* d_out, int out_size, void* d_ws, size_t ws_size,
                              hipStream_t stream) {
    const float* h_stack   = (const float*)d_in[0];
    const float* base_conf = (const float*)d_in[1];
    const float* kW1 = (const float*)d_in[2];
    const float* kb1 = (const float*)d_in[3];
    const float* kW2 = (const float*)d_in[4];
    const float* kb2 = (const float*)d_in[5];
    const float* lW1 = (const float*)d_in[6];
    const float* lb1 = (const float*)d_in[7];
    const float* lW2 = (const float*)d_in[8];
    const float* lb2 = (const float*)d_in[9];
    const float* dW1 = (const float*)d_in[10];
    const float* db1 = (const float*)d_in[11];
    const float* dW2 = (const float*)d_in[12];
    const float* db2 = (const float*)d_in[13];
    const float* kwp = (const float*)d_in[14];
    const float* lwp = (const float*)d_in[15];
    const float* iwp = (const float*)d_in[16];
    const float* tmpp= (const float*)d_in[17];
    float* out = (float*)d_out;

    hipLaunchKernelGGL(pack_A, dim3(11264), dim3(256), 0, stream, h_stack);
    hipLaunchKernelGGL(pack_weights, dim3(1536), dim3(256), 0, stream, kW1, lW1, dW1);

    hipFuncSetAttribute((const void*)energy_mfma,
                        hipFuncAttributeMaxDynamicSharedMemorySize, LDS_TOTAL);
    hipLaunchKernelGGL(energy_mfma, dim3(NBLOCKS), dim3(768), LDS_TOTAL, stream,
                       kb1, kW2, lb1, lW2, db1, dW2);

    hipLaunchKernelGGL(finalize, dim3(8), dim3(256), 0, stream,
                       base_conf, kb2, lb2, db2, kwp, lwp, iwp, tmpp, out);
}